// Round 5
// baseline (301.320 us; speedup 1.0000x reference)
//
#include <hip/hip_runtime.h>

#define DIM 128
#define NHEAD 64
#define NROT 8128
#define NSEG 10
#define MHEAD 89088            // sum of n_s^2 floats per head
#define NUNIT 18               // chain (seg,colblock) units per head

typedef float f4 __attribute__((ext_vector_type(4)));

__device__ const int SEG_A[NSEG]   = {0,8,16,24,32,40,48,56,64,80};
__device__ const int SEG_NG[NSEG]  = {1,1,1,1,1,1,1,1,2,6};
__device__ const int SEG_N[NSEG]   = {128,120,112,104,96,88,80,72,64,48};
__device__ const int SEG_OFF[NSEG] = {0,16384,30784,43328,54144,63360,71104,77504,82688,86784};
__device__ const signed char U_SEG[NUNIT] = {0,0,1,1,2,2,3,3,4,4,5,5,6,6,7,7,8,9};
__device__ const signed char U_CB[NUNIT]  = {0,1,0,1,0,1,0,1,0,1,0,1,0,1,0,1,0,0};

// |theta| <= ~0.06: degree-5/4 Taylor, error ~1e-11
__device__ __forceinline__ void sincos_poly(float x, float& sn, float& cn) {
    float x2 = x * x;
    sn = x * fmaf(x2, fmaf(x2, 8.33333333e-3f, -1.66666667e-1f), 1.0f);
    cn = fmaf(x2, fmaf(x2, 4.16666667e-2f, -0.5f), 1.0f);
}

struct Row { f4 q0, q1, q2, q3; };   // 8 (c,s) pairs for one trailing row

#define ROTP(c, s, T, v) { float pt = p[T]; p[T] = fmaf((c), pt, (s) * (v)); \
                           (v) = fmaf((c), (v), -((s) * pt)); }

__device__ __forceinline__ void rot8(const Row& r, float p[8], float& v) {
    ROTP(r.q0.x, r.q0.y, 0, v) ROTP(r.q0.z, r.q0.w, 1, v)
    ROTP(r.q1.x, r.q1.y, 2, v) ROTP(r.q1.z, r.q1.w, 3, v)
    ROTP(r.q2.x, r.q2.y, 4, v) ROTP(r.q2.z, r.q2.w, 5, v)
    ROTP(r.q3.x, r.q3.y, 6, v) ROTP(r.q3.z, r.q3.w, 7, v)
}

// ---- Phase 1: per-segment chain (UNCHANGED from R4 — known-good M producer) ----
__global__ __launch_bounds__(64, 1)
void chain_seg(const float* __restrict__ th_all, float* __restrict__ dst, int mono)
{
    __shared__ float Q[DIM][64];
    __shared__ __align__(16) float csx[56 + 8 * 120 * 2];

    const int lane = threadIdx.x;
    const int head = blockIdx.x & 63;
    const int unit = blockIdx.x >> 6;

    int s, cb, A_lo, ng, n;
    if (mono) { s = 0; cb = unit; A_lo = 0; ng = 16; n = 128; }
    else      { s = U_SEG[unit]; cb = U_CB[unit];
                A_lo = SEG_A[s]; ng = SEG_NG[s]; n = SEG_N[s]; }
    const int P = A_lo;
    const int col_local = cb * 64 + lane;
    const int col_glob  = P + col_local;
    const float* __restrict__ th = th_all + head * NROT;

    for (int r = P; r < DIM; ++r)
        Q[r][lane] = (r == col_glob) ? 1.0f : 0.0f;

    #pragma unroll 1
    for (int g = 0; g < ng; ++g) {
        const int a0  = P + 8 * g;
        const int ntr = 120 - a0;
        const int ne  = 8 * ntr;

        __syncthreads();
        float thx[15];
        #pragma unroll
        for (int it = 0; it < 15; ++it) {
            if (it * 64 < ne) {
                int e = lane + it * 64;
                int t = e & 7, jrel = e >> 3;
                int i = a0 + t;
                thx[it] = th[((i * (255 - i)) >> 1) + jrel + 7 - t];
            }
        }
        float thi = 0.0f;
        if (lane < 28) {
            int t1 = 0, rem = lane;
            while (rem >= 7 - t1) { rem -= 7 - t1; ++t1; }
            int t2 = t1 + 1 + rem;
            int i  = a0 + t1;
            thi = th[((i * (255 - i)) >> 1) + (t2 - t1 - 1)];
        }
        #pragma unroll
        for (int it = 0; it < 15; ++it) {
            if (it * 64 < ne) {
                int e = lane + it * 64;
                float sn, cn; sincos_poly(thx[it], sn, cn);
                csx[56 + 2 * e] = cn; csx[56 + 2 * e + 1] = sn;
            }
        }
        if (lane < 28) {
            float sn, cn; sincos_poly(thi, sn, cn);
            csx[2 * lane] = cn; csx[2 * lane + 1] = sn;
        }
        __syncthreads();

        float p[8];
        #pragma unroll
        for (int t = 0; t < 8; ++t) p[t] = Q[a0 + t][lane];

        {
            int idx = 0;
            #pragma unroll
            for (int t1 = 0; t1 < 8; ++t1) {
                #pragma unroll
                for (int t2 = t1 + 1; t2 < 8; ++t2) {
                    float c = csx[2 * idx], sn = csx[2 * idx + 1];
                    float pa = p[t1];
                    p[t1] = fmaf(c, pa,    sn * p[t2]);
                    p[t2] = fmaf(c, p[t2], -(sn * pa));
                    ++idx;
                }
            }
        }

        if (ntr > 0) {
            const float* cs = csx + 56;
            const int base = a0 + 8;
            Row A0, A1, B0, B1;
            float vA0, vA1, vB0, vB1;
            auto ldrow = [&](Row& R, float& v, int r) {
                const f4* c4 = (const f4*)(cs + 16 * r);
                R.q0 = c4[0]; R.q1 = c4[1]; R.q2 = c4[2]; R.q3 = c4[3];
                v = Q[base + r][lane];
            };
            ldrow(A0, vA0, 0); ldrow(A1, vA1, 1);
            #pragma unroll 1
            for (int r = 0; r < ntr; r += 4) {
                ldrow(B0, vB0, r + 2); ldrow(B1, vB1, r + 3);
                rot8(A0, p, vA0); rot8(A1, p, vA1);
                Q[base + r][lane]     = vA0;
                Q[base + r + 1][lane] = vA1;
                if (r + 4 < ntr) { ldrow(A0, vA0, r + 4); ldrow(A1, vA1, r + 5); }
                rot8(B0, p, vB0); rot8(B1, p, vB1);
                Q[base + r + 2][lane] = vB0;
                Q[base + r + 3][lane] = vB1;
            }
        }

        #pragma unroll
        for (int t = 0; t < 8; ++t) Q[a0 + t][lane] = p[t];
    }

    if (col_local < n) {
        if (mono) {
            float* o = dst + head * (DIM * DIM) + col_glob;
            #pragma unroll 1
            for (int r = 0; r < DIM; ++r) o[r * DIM] = Q[r][lane];
        } else {
            float* o = dst + head * MHEAD + SEG_OFF[s] + col_local;
            #pragma unroll 1
            for (int r = P; r < DIM; ++r) o[(r - P) * n] = Q[r][lane];
        }
    }
}

// ---- Phase 2: compose with register-resident A and scalar-pipe M stream ----
// Block = (head, 64-col half), 4 waves. Wave w holds A rows [32w,32w+32) in regs.
// Wave w's k-range for segment P: [32w + K0, 32w + 32), K0 in {0,8,16,24,32}.
template<int K0>
__device__ __forceinline__ void seg_rows(
    const float* __restrict__ Ms, int P, int n, int klo,
    const float (&aold)[32], float (&anew)[32],
    float (*red)[32][64], int w, int lane)
{
    #pragma unroll 1
    for (int q = 0; q < 4; ++q) {
        if (32 * (q + 1) <= P) continue;       // block-uniform skip (no barriers)
        const int lo = 32 * q;

        float acc[32];
        #pragma unroll
        for (int i = 0; i < 32; ++i) acc[i] = 0.0f;

        if constexpr (K0 < 32) {
            #pragma unroll
            for (int i = 0; i < 32; ++i) {
                if (lo + i >= P) {             // uniform guard
                    const float* __restrict__ Mr =
                        Ms + (long)(lo + i - P) * n + (klo - P);
                    const f4* __restrict__ Mr4 = (const f4*)Mr;
                    float a0 = 0.f, a1 = 0.f, a2 = 0.f, a3 = 0.f;
                    #pragma unroll
                    for (int j = 0; j < (32 - K0) / 4; ++j) {
                        f4 mv = Mr4[j];
                        a0 = fmaf(mv.x, aold[K0 + 4 * j + 0], a0);
                        a1 = fmaf(mv.y, aold[K0 + 4 * j + 1], a1);
                        a2 = fmaf(mv.z, aold[K0 + 4 * j + 2], a2);
                        a3 = fmaf(mv.w, aold[K0 + 4 * j + 3], a3);
                    }
                    acc[i] = (a0 + a1) + (a2 + a3);
                }
            }
        }

        #pragma unroll
        for (int i = 0; i < 32; ++i)
            if (lo + i >= P) red[w][i][lane] = acc[i];
        __syncthreads();

        if (w == q) {                          // wave-uniform: owner sums
            #pragma unroll
            for (int i = 0; i < 32; ++i)
                if (lo + i >= P)
                    anew[i] = (red[0][i][lane] + red[1][i][lane])
                            + (red[2][i][lane] + red[3][i][lane]);
        }
        __syncthreads();
    }
}

__global__ __launch_bounds__(256, 1)
void compose(const float* __restrict__ M, float* __restrict__ out)
{
    __shared__ float red[4][32][64];           // 32 KB reduce buffer

    const int tid  = threadIdx.x;
    const int lane = tid & 63;
    const int w    = __builtin_amdgcn_readfirstlane(tid >> 6);  // uniform wave id
    const int head = blockIdx.x & 63;          // cb*64+head -> both halves on XCD head%8
    const int cb   = blockIdx.x >> 6;
    const float* __restrict__ Mh = M + (size_t)head * MHEAD;

    float aold[32], anew[32];
    #pragma unroll
    for (int i = 0; i < 32; ++i)
        aold[i] = Mh[(32 * w + i) * DIM + cb * 64 + lane];   // A init = M_0 slice

    #pragma unroll 1
    for (int s = 1; s < NSEG; ++s) {
        const int P = SEG_A[s], n = SEG_N[s];
        const float* __restrict__ Ms = Mh + SEG_OFF[s];
        int kreg = P - 32 * w;
        kreg = kreg < 0 ? 0 : (kreg > 32 ? 32 : kreg);
        const int klo = 32 * w + kreg;
        switch (kreg) {                         // uniform per wave
            case 0:  seg_rows<0 >(Ms, P, n, klo, aold, anew, red, w, lane); break;
            case 8:  seg_rows<8 >(Ms, P, n, klo, aold, anew, red, w, lane); break;
            case 16: seg_rows<16>(Ms, P, n, klo, aold, anew, red, w, lane); break;
            case 24: seg_rows<24>(Ms, P, n, klo, aold, anew, red, w, lane); break;
            default: seg_rows<32>(Ms, P, n, klo, aold, anew, red, w, lane); break;
        }
        #pragma unroll
        for (int i = 0; i < 32; ++i)            // commit new rows (>= P only)
            if (32 * w + i >= P) aold[i] = anew[i];
    }

    float* o = out + (size_t)head * (DIM * DIM) + cb * 64 + lane;
    #pragma unroll
    for (int i = 0; i < 32; ++i)
        o[(32 * w + i) * DIM] = aold[i];
}

extern "C" void kernel_launch(void* const* d_in, const int* in_sizes, int n_in,
                              void* d_out, int out_size, void* d_ws, size_t ws_size,
                              hipStream_t stream) {
    const float* thetas = (const float*)d_in[0];
    float* out = (float*)d_out;
    const size_t need = (size_t)NHEAD * MHEAD * sizeof(float);  // 21.7 MB

    if (ws_size >= need) {
        float* Mws = (float*)d_ws;
        chain_seg<<<dim3(NUNIT * NHEAD), dim3(64), 0, stream>>>(thetas, Mws, 0);
        compose<<<dim3(2 * NHEAD), dim3(256), 0, stream>>>(Mws, out);
    } else {
        chain_seg<<<dim3(2 * NHEAD), dim3(64), 0, stream>>>(thetas, out, 1);
    }
}

// Round 6
// 94.002 us; speedup vs baseline: 3.2055x; 3.2055x over previous
//
#include <hip/hip_runtime.h>

#define DIM 128
#define NHEAD 64
#define NROT 8128
#define NSEG 10
#define MHEAD 89088            // sum of n_s^2 floats per head
#define NUNIT 18               // chain (seg,colblock) units per head

typedef float f4 __attribute__((ext_vector_type(4)));

__device__ const int SEG_A[NSEG]   = {0,8,16,24,32,40,48,56,64,80};
__device__ const int SEG_NG[NSEG]  = {1,1,1,1,1,1,1,1,2,6};
__device__ const int SEG_N[NSEG]   = {128,120,112,104,96,88,80,72,64,48};
__device__ const int SEG_OFF[NSEG] = {0,16384,30784,43328,54144,63360,71104,77504,82688,86784};
__device__ const signed char U_SEG[NUNIT] = {0,0,1,1,2,2,3,3,4,4,5,5,6,6,7,7,8,9};
__device__ const signed char U_CB[NUNIT]  = {0,1,0,1,0,1,0,1,0,1,0,1,0,1,0,1,0,0};

// |theta| <= ~0.06: degree-5/4 Taylor, error ~1e-11
__device__ __forceinline__ void sincos_poly(float x, float& sn, float& cn) {
    float x2 = x * x;
    sn = x * fmaf(x2, fmaf(x2, 8.33333333e-3f, -1.66666667e-1f), 1.0f);
    cn = fmaf(x2, fmaf(x2, 4.16666667e-2f, -0.5f), 1.0f);
}

struct Row { f4 q0, q1, q2, q3; };

#define ROTP(c, s, T, v) { float pt = p[T]; p[T] = fmaf((c), pt, (s) * (v)); \
                           (v) = fmaf((c), (v), -((s) * pt)); }

__device__ __forceinline__ void rot8(const Row& r, float p[8], float& v) {
    ROTP(r.q0.x, r.q0.y, 0, v) ROTP(r.q0.z, r.q0.w, 1, v)
    ROTP(r.q1.x, r.q1.y, 2, v) ROTP(r.q1.z, r.q1.w, 3, v)
    ROTP(r.q2.x, r.q2.y, 4, v) ROTP(r.q2.z, r.q2.w, 5, v)
    ROTP(r.q3.x, r.q3.y, 6, v) ROTP(r.q3.z, r.q3.w, 7, v)
}

// ---- Phase 1: per-segment chain; stores M^T (non-mono) for compose ----
__global__ __launch_bounds__(64, 1)
void chain_seg(const float* __restrict__ th_all, float* __restrict__ dst, int mono)
{
    __shared__ float Q[DIM][65];                 // pad 65: transposed read is conflict-free
    __shared__ __align__(16) float csx[56 + 8 * 120 * 2];

    const int lane = threadIdx.x;
    const int head = blockIdx.x & 63;
    const int unit = blockIdx.x >> 6;

    int s, cb, ng, n;
    if (mono) { s = 0; cb = unit; ng = 16; n = 128; }
    else      { s = U_SEG[unit]; cb = U_CB[unit]; ng = SEG_NG[s]; n = SEG_N[s]; }
    const int P = mono ? 0 : SEG_A[s];
    const int col_local = cb * 64 + lane;
    const int col_glob  = P + col_local;
    const float* __restrict__ th = th_all + head * NROT;

    for (int r = P; r < DIM; ++r)
        Q[r][lane] = (r == col_glob) ? 1.0f : 0.0f;

    #pragma unroll 1
    for (int g = 0; g < ng; ++g) {
        const int a0  = P + 8 * g;
        const int ntr = 120 - a0;
        const int ne  = 8 * ntr;

        __syncthreads();
        float thx[15];
        #pragma unroll
        for (int it = 0; it < 15; ++it) {
            if (it * 64 < ne) {
                int e = lane + it * 64;
                int t = e & 7, jrel = e >> 3;
                int i = a0 + t;
                thx[it] = th[((i * (255 - i)) >> 1) + jrel + 7 - t];
            }
        }
        float thi = 0.0f;
        if (lane < 28) {
            int t1 = 0, rem = lane;
            while (rem >= 7 - t1) { rem -= 7 - t1; ++t1; }
            int t2 = t1 + 1 + rem;
            int i  = a0 + t1;
            thi = th[((i * (255 - i)) >> 1) + (t2 - t1 - 1)];
        }
        #pragma unroll
        for (int it = 0; it < 15; ++it) {
            if (it * 64 < ne) {
                int e = lane + it * 64;
                float sn, cn; sincos_poly(thx[it], sn, cn);
                csx[56 + 2 * e] = cn; csx[56 + 2 * e + 1] = sn;
            }
        }
        if (lane < 28) {
            float sn, cn; sincos_poly(thi, sn, cn);
            csx[2 * lane] = cn; csx[2 * lane + 1] = sn;
        }
        __syncthreads();

        float p[8];
        #pragma unroll
        for (int t = 0; t < 8; ++t) p[t] = Q[a0 + t][lane];

        {
            int idx = 0;
            #pragma unroll
            for (int t1 = 0; t1 < 8; ++t1) {
                #pragma unroll
                for (int t2 = t1 + 1; t2 < 8; ++t2) {
                    float c = csx[2 * idx], sn = csx[2 * idx + 1];
                    float pa = p[t1];
                    p[t1] = fmaf(c, pa,    sn * p[t2]);
                    p[t2] = fmaf(c, p[t2], -(sn * pa));
                    ++idx;
                }
            }
        }

        if (ntr > 0) {
            const float* cs = csx + 56;
            const int base = a0 + 8;
            Row A0, A1, B0, B1;
            float vA0, vA1, vB0, vB1;
            auto ldrow = [&](Row& R, float& v, int r) {
                const f4* c4 = (const f4*)(cs + 16 * r);
                R.q0 = c4[0]; R.q1 = c4[1]; R.q2 = c4[2]; R.q3 = c4[3];
                v = Q[base + r][lane];
            };
            ldrow(A0, vA0, 0); ldrow(A1, vA1, 1);
            #pragma unroll 1
            for (int r = 0; r < ntr; r += 4) {
                ldrow(B0, vB0, r + 2); ldrow(B1, vB1, r + 3);
                rot8(A0, p, vA0); rot8(A1, p, vA1);
                Q[base + r][lane]     = vA0;
                Q[base + r + 1][lane] = vA1;
                if (r + 4 < ntr) { ldrow(A0, vA0, r + 4); ldrow(A1, vA1, r + 5); }
                rot8(B0, p, vB0); rot8(B1, p, vB1);
                Q[base + r + 2][lane] = vB0;
                Q[base + r + 3][lane] = vB1;
            }
        }

        #pragma unroll
        for (int t = 0; t < 8; ++t) Q[a0 + t][lane] = p[t];
    }

    __syncthreads();     // M^T store reads other lanes' columns

    if (mono) {
        float* o = dst + head * (DIM * DIM) + col_glob;
        #pragma unroll 1
        for (int r = 0; r < DIM; ++r) o[r * DIM] = Q[r][lane];
    } else {
        // store M^T: MT[c][r] = Q[P+r][c], coalesced over r, conflict-free LDS reads
        const int ncol = (n - cb * 64) < 64 ? (n - cb * 64) : 64;
        float* o = dst + (size_t)head * MHEAD + SEG_OFF[s];
        #pragma unroll 1
        for (int cc = 0; cc < ncol; ++cc) {
            const int cg = cb * 64 + cc;
            if (lane < n)      o[cg * n + lane]      = Q[P + lane][cc];
            if (lane + 64 < n) o[cg * n + lane + 64] = Q[P + lane + 64][cc];
        }
    }
}

// ---- Phase 2: textbook LDS-tiled f32 GEMM compose ----
// Block = (head, 32-col quarter). A slice [128][32] in LDS; per segment s>=1:
// A[P:,:] = M_s * A[P:,:], M^T streamed in k-chunks of 8 (double-buffered).
__device__ __forceinline__ void fma4(f4& acc, float m, const f4& a) {
    acc.x = fmaf(m, a.x, acc.x); acc.y = fmaf(m, a.y, acc.y);
    acc.z = fmaf(m, a.z, acc.z); acc.w = fmaf(m, a.w, acc.w);
}

__global__ __launch_bounds__(256, 1)
void compose(const float* __restrict__ M, float* __restrict__ out)
{
    __shared__ float A_sh[DIM][36];          // 18.4 KB, f4-aligned rows
    __shared__ float MT_sh[2][8][132];       // 8.4 KB double-buffered k-chunk

    const int tid  = threadIdx.x;
    const int head = blockIdx.x & 63;        // all 4 quarters of a head -> same XCD
    const int cq   = blockIdx.x >> 6;
    const int c0   = cq * 32;
    const float* __restrict__ Mh = M + (size_t)head * MHEAD;

    // A init = M0 slice (M0 stored transposed: M0T[c][r] at c*128+r) — coalesced in r
    for (int idx = tid; idx < 32 * DIM; idx += 256) {
        int c = idx >> 7, r = idx & 127;
        A_sh[r][c] = Mh[(c0 + c) * DIM + r];
    }

    const int tx = tid & 7;                  // col group: local cols 4*tx..+4
    const int ty = tid >> 3;                 // row group: rows 4*ty..+4
    const int rb = ty * 4;
    const int cl = tx * 4;
    const int skk = tid >> 5;                // staging: k-row 0..7
    const int si4 = tid & 31;                // staging: f4 index in row

    __syncthreads();

    #pragma unroll 1
    for (int s = 1; s < NSEG; ++s) {
        const int P = SEG_A[s], n = SEG_N[s];
        const float* __restrict__ Ms = Mh + SEG_OFF[s];
        const int n4 = n >> 2;
        const bool stg = si4 < n4;
        const bool act = rb < n;

        // stage chunk 0 into buf 0
        if (stg) *(f4*)&MT_sh[0][skk][si4 * 4] = *(const f4*)&Ms[skk * n + si4 * 4];
        __syncthreads();

        f4 acc0 = {0,0,0,0}, acc1 = {0,0,0,0}, acc2 = {0,0,0,0}, acc3 = {0,0,0,0};
        int buf = 0;
        #pragma unroll 1
        for (int k0 = 0; k0 < n; k0 += 8) {
            // T14 split: issue next chunk's load early, write to LDS after compute
            f4 nxt;
            const bool have = (k0 + 8 < n) && stg;
            if (have) nxt = *(const f4*)&Ms[(k0 + 8 + skk) * n + si4 * 4];
            if (act) {
                #pragma unroll
                for (int kk = 0; kk < 8; ++kk) {
                    const f4 m4 = *(const f4*)&MT_sh[buf][kk][rb];      // M[rb..rb+4][k]
                    const f4 a4 = *(const f4*)&A_sh[P + k0 + kk][cl];
                    fma4(acc0, m4.x, a4);
                    fma4(acc1, m4.y, a4);
                    fma4(acc2, m4.z, a4);
                    fma4(acc3, m4.w, a4);
                }
            }
            if (have) *(f4*)&MT_sh[buf ^ 1][skk][si4 * 4] = nxt;
            __syncthreads();
            buf ^= 1;
        }

        if (act) {
            *(f4*)&A_sh[P + rb + 0][cl] = acc0;
            *(f4*)&A_sh[P + rb + 1][cl] = acc1;
            *(f4*)&A_sh[P + rb + 2][cl] = acc2;
            *(f4*)&A_sh[P + rb + 3][cl] = acc3;
        }
        __syncthreads();
    }

    // output: f4 stores, coalesced (8 f4 = 128B per 8 consecutive threads)
    float* o = out + (size_t)head * (DIM * DIM) + c0;
    #pragma unroll 1
    for (int idx = tid; idx < DIM * 8; idx += 256) {
        int r = idx >> 3, c4 = (idx & 7) * 4;
        *(f4*)&o[r * DIM + c4] = *(const f4*)&A_sh[r][c4];
    }
}

extern "C" void kernel_launch(void* const* d_in, const int* in_sizes, int n_in,
                              void* d_out, int out_size, void* d_ws, size_t ws_size,
                              hipStream_t stream) {
    const float* thetas = (const float*)d_in[0];
    float* out = (float*)d_out;
    const size_t need = (size_t)NHEAD * MHEAD * sizeof(float);  // 21.7 MB

    if (ws_size >= need) {
        float* Mws = (float*)d_ws;
        chain_seg<<<dim3(NUNIT * NHEAD), dim3(64), 0, stream>>>(thetas, Mws, 0);
        compose<<<dim3(4 * NHEAD), dim3(256), 0, stream>>>(Mws, out);
    } else {
        chain_seg<<<dim3(2 * NHEAD), dim3(64), 0, stream>>>(thetas, out, 1);
    }
}